// Round 1
// baseline (4347.765 us; speedup 1.0000x reference)
//
#include <hip/hip_runtime.h>
#include <hip/hip_bf16.h>

// Problem constants
#define NN 10000
#define EE 160000
#define CC 4
#define CF 16
#define RR 7
#define HH 256
#define EIN 560          // 2H + CF + 2CF
#define NIN 2048         // R*H + H
#define EPSV 1e-5f

__device__ __forceinline__ float silu_f(float v) {
    return v / (1.f + __expf(-v));
}

// ---------------- small prep kernels ----------------

__global__ __launch_bounds__(256) void ca_kernel(
    const float* __restrict__ attr, const float* __restrict__ cw,
    float* __restrict__ ca)
{
    int t = blockIdx.x * 256 + threadIdx.x;   // N*CF items
    if (t < NN * CF) {
        int n = t >> 4, f = t & 15;
        float s = 0.f, cs = 0.f;
        #pragma unroll
        for (int c = 0; c < CC; ++c) {
            float w = cw[n * CC + c];
            s  += attr[(n * CC + c) * CF + f] * w;
            cs += w;
        }
        ca[t] = s / cs;
    }
}

__global__ __launch_bounds__(256) void deg_kernel(
    const int* __restrict__ el, float* __restrict__ deg)
{
    int e = blockIdx.x * 256 + threadIdx.x;
    if (e < EE) atomicAdd(&deg[el[e * 3]], 1.f);
}

// ---------------- fused edge kernel ----------------
// 16 edges per block, 256 threads = 4 waves.
// Wave w owns edges w*4..w*4+3; each thread computes outputs j = lane + 64*q, q=0..3.

template<int K>
__device__ __forceinline__ void mlp_stage(
    float (&mbuf)[16][EIN], int wv, int lane,
    const float* __restrict__ W, const float* __restrict__ bv,
    float (&acc)[4][4])
{
    #pragma unroll
    for (int q = 0; q < 4; ++q) {
        float bb = bv[lane + 64 * q];
        #pragma unroll
        for (int ee = 0; ee < 4; ++ee) acc[q][ee] = bb;
    }
    for (int i = 0; i < K; i += 4) {
        float4 mv[4];
        #pragma unroll
        for (int ee = 0; ee < 4; ++ee)
            mv[ee] = *(const float4*)&mbuf[wv * 4 + ee][i];
        #pragma unroll
        for (int q = 0; q < 4; ++q) {
            const float* wp = W + i * HH + lane + 64 * q;
            float w0 = wp[0], w1 = wp[HH], w2 = wp[2 * HH], w3 = wp[3 * HH];
            #pragma unroll
            for (int ee = 0; ee < 4; ++ee)
                acc[q][ee] += w0 * mv[ee].x + w1 * mv[ee].y
                            + w2 * mv[ee].z + w3 * mv[ee].w;
        }
    }
}

__global__ __launch_bounds__(256) void edge_kernel(
    const float* __restrict__ h, const float* __restrict__ x,
    const int* __restrict__ el, const float* __restrict__ cw,
    const float* __restrict__ ew, const float* __restrict__ ca,
    const float* __restrict__ W_rad, const float* __restrict__ b_rad,
    const float* __restrict__ W_e1, const float* __restrict__ b_e1,
    const float* __restrict__ W_e2, const float* __restrict__ b_e2,
    const float* __restrict__ W_c1, const float* __restrict__ b_c1,
    const float* __restrict__ W_c2,
    float* __restrict__ agg, float* __restrict__ xacc)
{
    __shared__ __align__(16) float mbuf[16][EIN];
    __shared__ __align__(16) float xdbuf[16][48];
    __shared__ float radbuf[16][16];
    __shared__ float phibuf[16][16];
    __shared__ int rowS[16], colS[16], relS[16];
    __shared__ float ewS[16], cwrS[16][4], cwcS[16][4];

    const int tid  = threadIdx.x;
    const int lane = tid & 63;
    const int wv   = tid >> 6;
    const int e0   = blockIdx.x * 16;

    if (tid < 16) {
        rowS[tid] = el[(e0 + tid) * 3 + 0];
        colS[tid] = el[(e0 + tid) * 3 + 1];
        relS[tid] = el[(e0 + tid) * 3 + 2];
        ewS[tid]  = ew[e0 + tid];
    }
    __syncthreads();
    if (tid < 64) {
        int e = tid >> 2, c = tid & 3;
        cwrS[e][c] = cw[rowS[e] * CC + c];
        cwcS[e][c] = cw[colS[e] * CC + c];
    }
    // stage h[row], h[col]
    #pragma unroll
    for (int e = 0; e < 16; ++e) {
        mbuf[e][tid]       = h[rowS[e] * HH + tid];
        mbuf[e][256 + tid] = h[colS[e] * HH + tid];
    }
    // stage ca[row], ca[col]
    {
        int e = tid >> 4, f = tid & 15;
        mbuf[e][528 + f] = ca[rowS[e] * CF + f];
        mbuf[e][544 + f] = ca[colS[e] * CF + f];
    }
    // xd = x[row][a] - x[col][b], 16 edges x 48
    for (int t = tid; t < 16 * 48; t += 256) {
        int e = t / 48, r = t - e * 48;
        int ab = r / 3, k = r - ab * 3;
        int a = ab >> 2, b = ab & 3;
        xdbuf[e][r] = x[rowS[e] * 12 + a * 3 + k] - x[colS[e] * 12 + b * 3 + k];
    }
    __syncthreads();
    // radial with channel-weight mask
    {
        int e = tid >> 4, ab = tid & 15;
        int a = ab >> 2, b = ab & 3;
        float d0 = xdbuf[e][ab * 3 + 0];
        float d1 = xdbuf[e][ab * 3 + 1];
        float d2 = xdbuf[e][ab * 3 + 2];
        radbuf[e][ab] = (d0 * d0 + d1 * d1 + d2 * d2) * cwrS[e][a] * cwcS[e][b];
    }
    __syncthreads();
    // rad_feat = silu(radial @ W_rad + b_rad)
    {
        int e = tid >> 4, f = tid & 15;
        float acc = b_rad[f];
        #pragma unroll
        for (int ab = 0; ab < 16; ++ab) acc += radbuf[e][ab] * W_rad[ab * CF + f];
        mbuf[e][512 + f] = silu_f(acc);
    }
    __syncthreads();

    float acc[4][4];

    // ---- e1: (E,560)@(560,256) ----
    mlp_stage<EIN>(mbuf, wv, lane, W_e1, b_e1, acc);
    __syncthreads();
    #pragma unroll
    for (int q = 0; q < 4; ++q)
        #pragma unroll
        for (int ee = 0; ee < 4; ++ee)
            mbuf[wv * 4 + ee][lane + 64 * q] = silu_f(acc[q][ee]);
    __syncthreads();

    // ---- e2: (E,256)@(256,256), m = silu(.)*ew ----
    mlp_stage<HH>(mbuf, wv, lane, W_e2, b_e2, acc);
    __syncthreads();
    #pragma unroll
    for (int q = 0; q < 4; ++q)
        #pragma unroll
        for (int ee = 0; ee < 4; ++ee) {
            int e = wv * 4 + ee;
            float m = silu_f(acc[q][ee]) * ewS[e];
            mbuf[e][lane + 64 * q] = m;
            atomicAdd(&agg[((size_t)colS[e] * RR + relS[e]) * HH + lane + 64 * q], m);
        }
    __syncthreads();

    // ---- c1: silu(m @ W_c1 + b_c1) ----
    mlp_stage<HH>(mbuf, wv, lane, W_c1, b_c1, acc);
    __syncthreads();
    #pragma unroll
    for (int q = 0; q < 4; ++q)
        #pragma unroll
        for (int ee = 0; ee < 4; ++ee)
            mbuf[wv * 4 + ee][lane + 64 * q] = silu_f(acc[q][ee]);
    __syncthreads();

    // ---- c2: phi = t2 @ W_c2  (16 outputs/edge) ----
    {
        int e = tid >> 4, ab = tid & 15;
        float p = 0.f;
        for (int i = 0; i < HH; i += 4) {
            float4 v = *(const float4*)&mbuf[e][i];
            p += v.x * W_c2[(i + 0) * 16 + ab] + v.y * W_c2[(i + 1) * 16 + ab]
               + v.z * W_c2[(i + 2) * 16 + ab] + v.w * W_c2[(i + 3) * 16 + ab];
        }
        phibuf[e][ab] = p;
    }
    __syncthreads();
    // trans[a][k] = mean_b xd[a][b][k]*phi[a][b]; scatter to xacc[row]
    if (tid < 16 * 12) {
        int e = tid / 12, r = tid - e * 12, a = r / 3, k = r - a * 3;
        float s = 0.f;
        #pragma unroll
        for (int b = 0; b < 4; ++b)
            s += xdbuf[e][(a * 4 + b) * 3 + k] * phibuf[e][a * 4 + b];
        atomicAdd(&xacc[rowS[e] * 12 + a * 3 + k], 0.25f * s);
    }
}

// ---------------- node kernels ----------------

#define NB 8
__global__ __launch_bounds__(256) void node1_kernel(
    const float* __restrict__ agg, const float* __restrict__ h,
    const float* __restrict__ W_n1, const float* __restrict__ b_n1,
    float* __restrict__ t1g)
{
    __shared__ __align__(16) float inbuf[NB][NIN];
    const int tid = threadIdx.x;
    const int n0  = blockIdx.x * NB;
    for (int nn = 0; nn < NB; ++nn) {
        const float* ap = agg + (size_t)(n0 + nn) * (RR * HH);
        for (int i = tid; i < RR * HH; i += 256) inbuf[nn][i] = ap[i];
        inbuf[nn][RR * HH + tid] = h[(n0 + nn) * HH + tid];
    }
    __syncthreads();
    float acc[NB];
    #pragma unroll
    for (int nn = 0; nn < NB; ++nn) acc[nn] = b_n1[tid];
    for (int i = 0; i < NIN; i += 4) {
        const float* wp = W_n1 + i * HH + tid;
        float w0 = wp[0], w1 = wp[HH], w2 = wp[2 * HH], w3 = wp[3 * HH];
        #pragma unroll
        for (int nn = 0; nn < NB; ++nn) {
            float4 v = *(const float4*)&inbuf[nn][i];
            acc[nn] += w0 * v.x + w1 * v.y + w2 * v.z + w3 * v.w;
        }
    }
    #pragma unroll
    for (int nn = 0; nn < NB; ++nn)
        t1g[(n0 + nn) * HH + tid] = silu_f(acc[nn]);
}

__global__ __launch_bounds__(256) void node2_kernel(
    const float* __restrict__ t1g, const float* __restrict__ W_n2,
    const float* __restrict__ b_n2, const float* __restrict__ ln_g,
    const float* __restrict__ ln_b, float* __restrict__ h_out)
{
    __shared__ __align__(16) float tbuf[HH];
    __shared__ float red[HH];
    const int n = blockIdx.x, j = threadIdx.x;
    tbuf[j] = t1g[n * HH + j];
    __syncthreads();
    float acc = b_n2[j];
    for (int i = 0; i < HH; i += 4) {
        float4 v = *(const float4*)&tbuf[i];
        const float* wp = W_n2 + i * HH + j;
        acc += v.x * wp[0] + v.y * wp[HH] + v.z * wp[2 * HH] + v.w * wp[3 * HH];
    }
    red[j] = acc;
    __syncthreads();
    for (int s = 128; s > 0; s >>= 1) { if (j < s) red[j] += red[j + s]; __syncthreads(); }
    float mu = red[0] * (1.f / 256.f);
    __syncthreads();
    red[j] = acc * acc;
    __syncthreads();
    for (int s = 128; s > 0; s >>= 1) { if (j < s) red[j] += red[j + s]; __syncthreads(); }
    float var = red[0] * (1.f / 256.f) - mu * mu;
    h_out[n * HH + j] = (acc - mu) * rsqrtf(var + EPSV) * ln_g[j] + ln_b[j];
}

__global__ __launch_bounds__(256) void xout_kernel(
    const float* __restrict__ x_in, const float* __restrict__ xacc,
    const float* __restrict__ deg, float* __restrict__ x_out)
{
    int t = blockIdx.x * 256 + threadIdx.x;
    if (t < NN * 12) {
        int n = t / 12;
        float c = fmaxf(deg[n], 1.f);
        x_out[t] = x_in[t] + xacc[t] / c;
    }
}

// ---------------- launcher ----------------

extern "C" void kernel_launch(void* const* d_in, const int* in_sizes, int n_in,
                              void* d_out, int out_size, void* d_ws, size_t ws_size,
                              hipStream_t stream)
{
    const float* input  = (const float*)d_in[0];
    const float* coords = (const float*)d_in[1];
    const float* cattr  = (const float*)d_in[2];
    const float* cwts   = (const float*)d_in[3];
    const float* ewts   = (const float*)d_in[4];
    const int*   elist  = (const int*)d_in[5];
    const float* W_rad  = (const float*)d_in[6];
    const float* b_rad  = (const float*)d_in[7];
    const float* W_e1   = (const float*)d_in[8];
    const float* b_e1   = (const float*)d_in[9];
    const float* W_e2   = (const float*)d_in[10];
    const float* b_e2   = (const float*)d_in[11];
    const float* W_c1   = (const float*)d_in[12];
    const float* b_c1   = (const float*)d_in[13];
    const float* W_c2   = (const float*)d_in[14];
    const float* W_n1   = (const float*)d_in[15];
    const float* b_n1   = (const float*)d_in[16];
    const float* W_n2   = (const float*)d_in[17];
    const float* b_n2   = (const float*)d_in[18];
    const float* ln_g   = (const float*)d_in[19];
    const float* ln_b   = (const float*)d_in[20];

    float* wsf  = (float*)d_ws;
    float* ca   = wsf;                      // N*16
    float* deg  = ca + (size_t)NN * CF;     // N
    float* agg  = deg + NN;                 // N*R*H
    float* xacc = agg + (size_t)NN * RR * HH; // N*12
    float* hbuf = xacc + (size_t)NN * 12;   // N*H
    float* xbuf = hbuf + (size_t)NN * HH;   // N*12
    float* t1g  = xbuf + (size_t)NN * 12;   // N*H

    hipMemsetAsync(deg, 0, (size_t)NN * sizeof(float), stream);
    ca_kernel<<<(NN * CF + 255) / 256, 256, 0, stream>>>(cattr, cwts, ca);
    deg_kernel<<<(EE + 255) / 256, 256, 0, stream>>>(elist, deg);

    for (int l = 0; l < 2; ++l) {
        const float* h_in = (l == 0) ? input  : hbuf;
        const float* x_in = (l == 0) ? coords : xbuf;
        float* h_out = (l == 0) ? hbuf : (float*)d_out;
        float* x_out = (l == 0) ? xbuf : ((float*)d_out + (size_t)NN * HH);

        hipMemsetAsync(agg, 0, (size_t)NN * RR * HH * sizeof(float), stream);
        hipMemsetAsync(xacc, 0, (size_t)NN * 12 * sizeof(float), stream);

        edge_kernel<<<EE / 16, 256, 0, stream>>>(
            h_in, x_in, elist, cwts, ewts, ca,
            W_rad + l * 256, b_rad + l * 16,
            W_e1 + (size_t)l * EIN * HH, b_e1 + l * HH,
            W_e2 + (size_t)l * HH * HH,  b_e2 + l * HH,
            W_c1 + (size_t)l * HH * HH,  b_c1 + l * HH,
            W_c2 + (size_t)l * HH * 16,
            agg, xacc);

        node1_kernel<<<NN / NB, 256, 0, stream>>>(
            agg, h_in, W_n1 + (size_t)l * NIN * HH, b_n1 + l * HH, t1g);

        node2_kernel<<<NN, 256, 0, stream>>>(
            t1g, W_n2 + (size_t)l * HH * HH, b_n2 + l * HH,
            ln_g + l * HH, ln_b + l * HH, h_out);

        xout_kernel<<<(NN * 12 + 255) / 256, 256, 0, stream>>>(
            x_in, xacc, deg, x_out);
    }
}

// Round 2
// 1268.340 us; speedup vs baseline: 3.4279x; 3.4279x over previous
//
#include <hip/hip_runtime.h>
#include <hip/hip_bf16.h>

#define NN 10000
#define EE 160000
#define CCH 4
#define CF 16
#define RR 7
#define HH 256
#define EPSV 1e-5f

typedef unsigned short ushort_t;
typedef __bf16 bf16x8 __attribute__((ext_vector_type(8)));
typedef float f32x4 __attribute__((ext_vector_type(4)));

__device__ __forceinline__ float silu_f(float v) {
    return v / (1.f + __expf(-v));
}

__device__ __forceinline__ ushort_t bf16u(float f) {
    unsigned int u = __builtin_bit_cast(unsigned int, f);
    u += 0x7fffu + ((u >> 16) & 1u);
    return (ushort_t)(u >> 16);
}

// ---------------- prep kernels ----------------

__global__ __launch_bounds__(256) void ca_kernel(
    const float* __restrict__ attr, const float* __restrict__ cw,
    float* __restrict__ ca)
{
    int t = blockIdx.x * 256 + threadIdx.x;
    if (t < NN * CF) {
        int n = t >> 4, f = t & 15;
        float s = 0.f, cs = 0.f;
        #pragma unroll
        for (int c = 0; c < CCH; ++c) {
            float w = cw[n * CCH + c];
            s  += attr[(n * CCH + c) * CF + f] * w;
            cs += w;
        }
        ca[t] = s / cs;
    }
}

__global__ __launch_bounds__(256) void deg_kernel(
    const int* __restrict__ el, float* __restrict__ deg)
{
    int e = blockIdx.x * 256 + threadIdx.x;
    if (e < EE) atomicAdd(&deg[el[e * 3]], 1.f);
}

__global__ __launch_bounds__(256) void cvt_kernel(
    const float* __restrict__ s, ushort_t* __restrict__ d, int n)
{
    int t = blockIdx.x * 256 + threadIdx.x;
    if (t < n) d[t] = bf16u(s[t]);
}

// Pack W (Kreal x N row-major fp32) into MFMA B-fragment order, bf16.
// grid = (KT, NTOT), 64 threads. out[((kt*NTOT+nt)*64+lane)*8 + j] =
// bf16(W[kt*32 + (lane>>4)*8 + j][nt*16 + (lane&15)]), zero-padded past Kreal.
__global__ __launch_bounds__(64) void pack_kernel(
    const float* __restrict__ W, ushort_t* __restrict__ out,
    int Kreal, int N)
{
    int kt = blockIdx.x, nt = blockIdx.y, NTOT = gridDim.y;
    int lane = threadIdx.x;
    int n = nt * 16 + (lane & 15);
    int kbase = kt * 32 + (lane >> 4) * 8;
    ushort_t* o = out + ((size_t)(kt * NTOT + nt) * 64 + lane) * 8;
    #pragma unroll
    for (int j = 0; j < 8; ++j) {
        int k = kbase + j;
        o[j] = (k < Kreal) ? bf16u(W[(size_t)k * N + n]) : (ushort_t)0;
    }
}

// ---------------- MFMA stage helpers ----------------
// A in LDS (32 rows, stride 584 bf16 = 73*16B, odd multiple of 16B).
// Wave w covers output cols [w*64, w*64+64) as 4 x 16-col tiles.

template<int KT, int NTOT>
__device__ __forceinline__ void mfma_stage32(
    const ushort_t (&A)[32][584], int colOff,
    const ushort_t* __restrict__ Wp, int w, int lane,
    f32x4 (&acc)[2][4])
{
    const f32x4 Z = {0.f, 0.f, 0.f, 0.f};
    #pragma unroll
    for (int mt = 0; mt < 2; ++mt)
        #pragma unroll
        for (int j = 0; j < 4; ++j) acc[mt][j] = Z;
    const int ar = lane & 15, aq = (lane >> 4) * 8;
    for (int kt = 0; kt < KT; ++kt) {
        bf16x8 a0 = *(const bf16x8*)&A[ar][colOff + kt * 32 + aq];
        bf16x8 a1 = *(const bf16x8*)&A[16 + ar][colOff + kt * 32 + aq];
        #pragma unroll
        for (int j = 0; j < 4; ++j) {
            bf16x8 b = *(const bf16x8*)(Wp + ((size_t)(kt * NTOT + w * 4 + j) * 64 + lane) * 8);
            acc[0][j] = __builtin_amdgcn_mfma_f32_16x16x32_bf16(a0, b, acc[0][j], 0, 0, 0);
            acc[1][j] = __builtin_amdgcn_mfma_f32_16x16x32_bf16(a1, b, acc[1][j], 0, 0, 0);
        }
    }
}

// ---------------- fused edge kernel (32 edges/block, MFMA) ----------------

__global__ __launch_bounds__(256) void edge_kernel(
    const int* __restrict__ el, const float* __restrict__ cw,
    const float* __restrict__ ew, const float* __restrict__ x,
    const ushort_t* __restrict__ hb16, const ushort_t* __restrict__ cab16,
    const float* __restrict__ W_rad, const float* __restrict__ b_rad,
    const ushort_t* __restrict__ pe1, const float* __restrict__ b_e1,
    const ushort_t* __restrict__ pe2, const float* __restrict__ b_e2,
    const ushort_t* __restrict__ pc1, const float* __restrict__ b_c1,
    const ushort_t* __restrict__ pc2,
    float* __restrict__ agg, float* __restrict__ xacc)
{
    __shared__ ushort_t abuf[32][584];   // K-major bf16: cols 0..575 = e1 input;
                                         // later cols 0..255 = t1/t2, 288..543 = m
    __shared__ float xdbuf[32][48];
    __shared__ float radbuf[32][16];     // reused as phi after c2
    __shared__ float phipart[4][32][16];
    __shared__ int rowS[32], colS[32], relS[32];
    __shared__ float ewS[32], cwrS[32][4], cwcS[32][4];

    const int tid = threadIdx.x, lane = tid & 63, w = tid >> 6;
    const int e0 = blockIdx.x * 32;

    if (tid < 32) {
        rowS[tid] = el[(e0 + tid) * 3 + 0];
        colS[tid] = el[(e0 + tid) * 3 + 1];
        relS[tid] = el[(e0 + tid) * 3 + 2];
        ewS[tid]  = ew[e0 + tid];
    }
    __syncthreads();
    {
        int e = (tid & 127) >> 2, c = tid & 3;
        if (tid < 128) cwrS[e][c] = cw[rowS[e] * CCH + c];
        else           cwcS[e][c] = cw[colS[e] * CCH + c];
    }
    // stage h[row], h[col] as bf16 (2 edges / iter, uint2 = 4 bf16)
    for (int it = 0; it < 16; ++it) {
        int e = it * 2 + (tid >> 7);
        int half = (tid >> 6) & 1;
        int idx = tid & 63;
        int node = half ? colS[e] : rowS[e];
        ((uint2*)&abuf[e][half * 256])[idx] =
            ((const uint2*)(hb16 + (size_t)node * 256))[idx];
    }
    // stage ca[row](cols 528..543), ca[col](544..559)
    for (int t = tid; t < 512; t += 256) {
        int e = t >> 4, s = t & 15;
        if (s < 8) ((unsigned int*)&abuf[e][528])[s] =
                       ((const unsigned int*)(cab16 + rowS[e] * 16))[s];
        else       ((unsigned int*)&abuf[e][544])[s - 8] =
                       ((const unsigned int*)(cab16 + colS[e] * 16))[s - 8];
    }
    // zero K-pad cols 560..575
    { int e = tid >> 3; ((unsigned int*)&abuf[e][560])[tid & 7] = 0; }
    // xd
    for (int t = tid; t < 32 * 48; t += 256) {
        int e = t / 48, r = t - e * 48;
        int ab = r / 3, k = r - ab * 3;
        int a = ab >> 2, b = ab & 3;
        xdbuf[e][r] = x[rowS[e] * 12 + a * 3 + k] - x[colS[e] * 12 + b * 3 + k];
    }
    __syncthreads();
    // radial
    for (int t = tid; t < 512; t += 256) {
        int e = t >> 4, ab = t & 15, a = ab >> 2, b = ab & 3;
        float d0 = xdbuf[e][ab * 3 + 0], d1 = xdbuf[e][ab * 3 + 1], d2 = xdbuf[e][ab * 3 + 2];
        radbuf[e][ab] = (d0 * d0 + d1 * d1 + d2 * d2) * cwrS[e][a] * cwcS[e][b];
    }
    __syncthreads();
    // rad_feat -> abuf cols 512..527
    for (int t = tid; t < 512; t += 256) {
        int e = t >> 4, f = t & 15;
        float acc = b_rad[f];
        #pragma unroll
        for (int ab = 0; ab < 16; ++ab) acc += radbuf[e][ab] * W_rad[ab * 16 + f];
        abuf[e][512 + f] = bf16u(silu_f(acc));
    }
    __syncthreads();

    f32x4 acc[2][4];
    const int ar = lane & 15, aq = (lane >> 4) * 8;

    // ---- e1 ----
    mfma_stage32<18, 16>(abuf, 0, pe1, w, lane, acc);
    __syncthreads();
    #pragma unroll
    for (int j = 0; j < 4; ++j) {
        int n = w * 64 + j * 16 + ar;
        float bj = b_e1[n];
        #pragma unroll
        for (int mt = 0; mt < 2; ++mt)
            #pragma unroll
            for (int r = 0; r < 4; ++r)
                abuf[mt * 16 + (lane >> 4) * 4 + r][n] = bf16u(silu_f(acc[mt][j][r] + bj));
    }
    __syncthreads();

    // ---- e2: m ----
    mfma_stage32<8, 16>(abuf, 0, pe2, w, lane, acc);
    __syncthreads();
    #pragma unroll
    for (int j = 0; j < 4; ++j) {
        int n = w * 64 + j * 16 + ar;
        float bj = b_e2[n];
        #pragma unroll
        for (int mt = 0; mt < 2; ++mt)
            #pragma unroll
            for (int r = 0; r < 4; ++r) {
                int e = mt * 16 + (lane >> 4) * 4 + r;
                float m = silu_f(acc[mt][j][r] + bj) * ewS[e];
                abuf[e][288 + n] = bf16u(m);
                atomicAdd(&agg[((size_t)colS[e] * RR + relS[e]) * HH + n], m);
            }
    }
    __syncthreads();

    // ---- c1 ----
    mfma_stage32<8, 16>(abuf, 288, pc1, w, lane, acc);
    __syncthreads();
    #pragma unroll
    for (int j = 0; j < 4; ++j) {
        int n = w * 64 + j * 16 + ar;
        float bj = b_c1[n];
        #pragma unroll
        for (int mt = 0; mt < 2; ++mt)
            #pragma unroll
            for (int r = 0; r < 4; ++r)
                abuf[mt * 16 + (lane >> 4) * 4 + r][n] = bf16u(silu_f(acc[mt][j][r] + bj));
    }
    __syncthreads();

    // ---- c2: phi (K split across waves, LDS reduce) ----
    {
        const f32x4 Z = {0.f, 0.f, 0.f, 0.f};
        f32x4 p0 = Z, p1 = Z;
        #pragma unroll
        for (int kk = 0; kk < 2; ++kk) {
            int kt = w * 2 + kk;
            bf16x8 a0 = *(const bf16x8*)&abuf[ar][kt * 32 + aq];
            bf16x8 a1 = *(const bf16x8*)&abuf[16 + ar][kt * 32 + aq];
            bf16x8 b = *(const bf16x8*)(pc2 + ((size_t)kt * 64 + lane) * 8);
            p0 = __builtin_amdgcn_mfma_f32_16x16x32_bf16(a0, b, p0, 0, 0, 0);
            p1 = __builtin_amdgcn_mfma_f32_16x16x32_bf16(a1, b, p1, 0, 0, 0);
        }
        #pragma unroll
        for (int r = 0; r < 4; ++r) {
            phipart[w][(lane >> 4) * 4 + r][ar] = p0[r];
            phipart[w][16 + (lane >> 4) * 4 + r][ar] = p1[r];
        }
    }
    __syncthreads();
    for (int t = tid; t < 512; t += 256) {
        int e = t >> 4, ab = t & 15;
        radbuf[e][ab] = phipart[0][e][ab] + phipart[1][e][ab]
                      + phipart[2][e][ab] + phipart[3][e][ab];
    }
    __syncthreads();
    // trans -> xacc
    for (int t = tid; t < 384; t += 256) {
        int e = t / 12, r = t - e * 12, a = r / 3, k = r - a * 3;
        float s = 0.f;
        #pragma unroll
        for (int b = 0; b < 4; ++b)
            s += xdbuf[e][(a * 4 + b) * 3 + k] * radbuf[e][a * 4 + b];
        atomicAdd(&xacc[rowS[e] * 12 + a * 3 + k], 0.25f * s);
    }
}

// ---------------- fused node kernel (n1 + n2 + LN, 16 nodes/block) ----------------

__global__ __launch_bounds__(256) void node_kernel(
    const float* __restrict__ agg, const float* __restrict__ hsrc,
    const ushort_t* __restrict__ pn1, const float* __restrict__ b_n1,
    const ushort_t* __restrict__ pn2, const float* __restrict__ b_n2,
    const float* __restrict__ ln_g, const float* __restrict__ ln_b,
    float* __restrict__ h_out, ushort_t* __restrict__ hb16o)
{
    __shared__ ushort_t nbuf[16][1032];   // one K-chunk (1024) bf16, stride 129*16B
    __shared__ ushort_t tbuf[16][264];
    __shared__ float h2buf[16][264];
    __shared__ float redS[16][16], red2S[16][16], muS[16], rsS[16];

    const int tid = threadIdx.x, lane = tid & 63, w = tid >> 6;
    const int n0 = blockIdx.x * 16;
    const int ar = lane & 15, aq = (lane >> 4) * 8;
    const f32x4 Z = {0.f, 0.f, 0.f, 0.f};

    f32x4 acc[4] = {Z, Z, Z, Z};
    for (int chunk = 0; chunk < 2; ++chunk) {
        for (int t = tid; t < 4096; t += 256) {
            int node = t >> 8, i4 = t & 255;
            int g4 = chunk * 256 + i4;        // float4 index over K=2048
            float4 v;
            if (g4 < 448) v = ((const float4*)(agg + (size_t)(n0 + node) * 1792))[g4];
            else          v = ((const float4*)(hsrc + (size_t)(n0 + node) * 256))[g4 - 448];
            ushort4 u;
            u.x = bf16u(v.x); u.y = bf16u(v.y); u.z = bf16u(v.z); u.w = bf16u(v.w);
            *(ushort4*)&nbuf[node][i4 * 4] = u;
        }
        __syncthreads();
        for (int kt = 0; kt < 32; ++kt) {
            bf16x8 a = *(const bf16x8*)&nbuf[ar][kt * 32 + aq];
            int ktg = chunk * 32 + kt;
            #pragma unroll
            for (int j = 0; j < 4; ++j) {
                bf16x8 b = *(const bf16x8*)(pn1 + ((size_t)(ktg * 16 + w * 4 + j) * 64 + lane) * 8);
                acc[j] = __builtin_amdgcn_mfma_f32_16x16x32_bf16(a, b, acc[j], 0, 0, 0);
            }
        }
        __syncthreads();
    }
    // t1 = silu(.)
    #pragma unroll
    for (int j = 0; j < 4; ++j) {
        int n = w * 64 + j * 16 + ar;
        float bj = b_n1[n];
        #pragma unroll
        for (int r = 0; r < 4; ++r)
            tbuf[(lane >> 4) * 4 + r][n] = bf16u(silu_f(acc[j][r] + bj));
    }
    __syncthreads();
    // n2
    f32x4 acc2[4] = {Z, Z, Z, Z};
    for (int kt = 0; kt < 8; ++kt) {
        bf16x8 a = *(const bf16x8*)&tbuf[ar][kt * 32 + aq];
        #pragma unroll
        for (int j = 0; j < 4; ++j) {
            bf16x8 b = *(const bf16x8*)(pn2 + ((size_t)(kt * 16 + w * 4 + j) * 64 + lane) * 8);
            acc2[j] = __builtin_amdgcn_mfma_f32_16x16x32_bf16(a, b, acc2[j], 0, 0, 0);
        }
    }
    float hv[4][4];
    #pragma unroll
    for (int j = 0; j < 4; ++j) {
        int n = w * 64 + j * 16 + ar;
        float bj = b_n2[n];
        #pragma unroll
        for (int r = 0; r < 4; ++r) {
            hv[j][r] = acc2[j][r] + bj;
            h2buf[(lane >> 4) * 4 + r][n] = hv[j][r];
        }
    }
    __syncthreads();
    {
        int node = tid >> 4, c = tid & 15;
        float s = 0.f, s2 = 0.f;
        #pragma unroll
        for (int i = 0; i < 16; ++i) {
            float v = h2buf[node][c * 16 + i];
            s += v; s2 += v * v;
        }
        redS[node][c] = s; red2S[node][c] = s2;
    }
    __syncthreads();
    if (tid < 16) {
        float s = 0.f, s2 = 0.f;
        #pragma unroll
        for (int c = 0; c < 16; ++c) { s += redS[tid][c]; s2 += red2S[tid][c]; }
        float mu = s * (1.f / 256.f);
        muS[tid] = mu;
        rsS[tid] = rsqrtf(s2 * (1.f / 256.f) - mu * mu + EPSV);
    }
    __syncthreads();
    #pragma unroll
    for (int j = 0; j < 4; ++j) {
        int n = w * 64 + j * 16 + ar;
        float g = ln_g[n], bb = ln_b[n];
        #pragma unroll
        for (int r = 0; r < 4; ++r) {
            int row = (lane >> 4) * 4 + r;
            float v = (hv[j][r] - muS[row]) * rsS[row] * g + bb;
            h_out[(size_t)(n0 + row) * HH + n] = v;
            hb16o[(size_t)(n0 + row) * HH + n] = bf16u(v);
        }
    }
}

__global__ __launch_bounds__(256) void xout_kernel(
    const float* __restrict__ x_in, const float* __restrict__ xacc,
    const float* __restrict__ deg, float* __restrict__ x_out)
{
    int t = blockIdx.x * 256 + threadIdx.x;
    if (t < NN * 12) {
        int n = t / 12;
        float c = fmaxf(deg[n], 1.f);
        x_out[t] = x_in[t] + xacc[t] / c;
    }
}

// ---------------- launcher ----------------

extern "C" void kernel_launch(void* const* d_in, const int* in_sizes, int n_in,
                              void* d_out, int out_size, void* d_ws, size_t ws_size,
                              hipStream_t stream)
{
    const float* input  = (const float*)d_in[0];
    const float* coords = (const float*)d_in[1];
    const float* cattr  = (const float*)d_in[2];
    const float* cwts   = (const float*)d_in[3];
    const float* ewts   = (const float*)d_in[4];
    const int*   elist  = (const int*)d_in[5];
    const float* W_rad  = (const float*)d_in[6];
    const float* b_rad  = (const float*)d_in[7];
    const float* W_e1   = (const float*)d_in[8];
    const float* b_e1   = (const float*)d_in[9];
    const float* W_e2   = (const float*)d_in[10];
    const float* b_e2   = (const float*)d_in[11];
    const float* W_c1   = (const float*)d_in[12];
    const float* b_c1   = (const float*)d_in[13];
    const float* W_c2   = (const float*)d_in[14];
    const float* W_n1   = (const float*)d_in[15];
    const float* b_n1   = (const float*)d_in[16];
    const float* W_n2   = (const float*)d_in[17];
    const float* b_n2   = (const float*)d_in[18];
    const float* ln_g   = (const float*)d_in[19];
    const float* ln_b   = (const float*)d_in[20];

    float* wsf  = (float*)d_ws;
    float* ca   = wsf;                          // 160000
    float* deg  = ca + 160000;                  // 10000
    float* agg  = deg + 10000;                  // 17,920,000
    float* xacc = agg + (size_t)NN * RR * HH;   // 120000
    float* hbuf = xacc + 120000;                // 2,560,000
    float* xbuf = hbuf + (size_t)NN * HH;       // 120000
    ushort_t* ub = (ushort_t*)(xbuf + 120000);
    ushort_t* hb16  = ub;                       // 2,560,000
    ushort_t* cab16 = hb16 + 2560000;           // 160,000
    ushort_t* pe1   = cab16 + 160000;           // 2 x 147456
    ushort_t* pe2   = pe1 + 294912;             // 2 x 65536
    ushort_t* pc1   = pe2 + 131072;             // 2 x 65536
    ushort_t* pc2   = pc1 + 131072;             // 2 x 4096
    ushort_t* pn1   = pc2 + 8192;               // 2 x 524288
    ushort_t* pn2   = pn1 + 1048576;            // 2 x 65536

    hipMemsetAsync(deg, 0, (size_t)NN * sizeof(float), stream);
    ca_kernel<<<(NN * CF + 255) / 256, 256, 0, stream>>>(cattr, cwts, ca);
    deg_kernel<<<(EE + 255) / 256, 256, 0, stream>>>(elist, deg);
    cvt_kernel<<<(NN * HH + 255) / 256, 256, 0, stream>>>(input, hb16, NN * HH);
    cvt_kernel<<<(NN * CF + 255) / 256, 256, 0, stream>>>(ca, cab16, NN * CF);

    for (int l = 0; l < 2; ++l) {
        pack_kernel<<<dim3(18, 16), 64, 0, stream>>>(W_e1 + (size_t)l * 560 * 256, pe1 + (size_t)l * 147456, 560, 256);
        pack_kernel<<<dim3(8, 16), 64, 0, stream>>>(W_e2 + (size_t)l * 65536, pe2 + (size_t)l * 65536, 256, 256);
        pack_kernel<<<dim3(8, 16), 64, 0, stream>>>(W_c1 + (size_t)l * 65536, pc1 + (size_t)l * 65536, 256, 256);
        pack_kernel<<<dim3(8, 1),  64, 0, stream>>>(W_c2 + (size_t)l * 4096,  pc2 + (size_t)l * 4096,  256, 16);
        pack_kernel<<<dim3(64, 16), 64, 0, stream>>>(W_n1 + (size_t)l * 524288, pn1 + (size_t)l * 524288, 2048, 256);
        pack_kernel<<<dim3(8, 16), 64, 0, stream>>>(W_n2 + (size_t)l * 65536, pn2 + (size_t)l * 65536, 256, 256);
    }

    for (int l = 0; l < 2; ++l) {
        const float* x_in = (l == 0) ? coords : xbuf;
        const float* h_in_f = (l == 0) ? input : hbuf;   // fp32 h for node-kernel tail
        float* h_out = (l == 0) ? hbuf : (float*)d_out;
        float* x_out = (l == 0) ? xbuf : ((float*)d_out + (size_t)NN * HH);

        hipMemsetAsync(agg, 0, (size_t)NN * RR * HH * sizeof(float), stream);
        hipMemsetAsync(xacc, 0, (size_t)NN * 12 * sizeof(float), stream);

        edge_kernel<<<EE / 32, 256, 0, stream>>>(
            elist, cwts, ewts, x_in, hb16, cab16,
            W_rad + l * 256, b_rad + l * 16,
            pe1 + (size_t)l * 147456, b_e1 + l * HH,
            pe2 + (size_t)l * 65536,  b_e2 + l * HH,
            pc1 + (size_t)l * 65536,  b_c1 + l * HH,
            pc2 + (size_t)l * 4096,
            agg, xacc);

        node_kernel<<<NN / 16, 256, 0, stream>>>(
            agg, h_in_f,
            pn1 + (size_t)l * 524288, b_n1 + l * HH,
            pn2 + (size_t)l * 65536,  b_n2 + l * HH,
            ln_g + l * HH, ln_b + l * HH,
            h_out, hb16);

        xout_kernel<<<(NN * 12 + 255) / 256, 256, 0, stream>>>(
            x_in, xacc, deg, x_out);
    }
}

// Round 3
// 816.500 us; speedup vs baseline: 5.3249x; 1.5534x over previous
//
#include <hip/hip_runtime.h>
#include <hip/hip_bf16.h>

#define NN 10000
#define EE 160000
#define CCH 4
#define CF 16
#define RR 7
#define HH 256
#define EPSV 1e-5f

typedef unsigned short ushort_t;
typedef __bf16 bf16x8 __attribute__((ext_vector_type(8)));
typedef float f32x4 __attribute__((ext_vector_type(4)));

__device__ __forceinline__ float silu_f(float v) {
    return v / (1.f + __expf(-v));
}

__device__ __forceinline__ ushort_t bf16u(float f) {
    unsigned int u = __builtin_bit_cast(unsigned int, f);
    u += 0x7fffu + ((u >> 16) & 1u);
    return (ushort_t)(u >> 16);
}

__device__ __forceinline__ float ubf2f(ushort_t u) {
    unsigned int v = ((unsigned int)u) << 16;
    return __builtin_bit_cast(float, v);
}

// ---------------- prep kernels ----------------

__global__ __launch_bounds__(256) void ca_kernel(
    const float* __restrict__ attr, const float* __restrict__ cw,
    float* __restrict__ ca)
{
    int t = blockIdx.x * 256 + threadIdx.x;
    if (t < NN * CF) {
        int n = t >> 4, f = t & 15;
        float s = 0.f, cs = 0.f;
        #pragma unroll
        for (int c = 0; c < CCH; ++c) {
            float w = cw[n * CCH + c];
            s  += attr[(n * CCH + c) * CF + f] * w;
            cs += w;
        }
        ca[t] = s / cs;
    }
}

__global__ __launch_bounds__(256) void deg_kernel(
    const int* __restrict__ el, float* __restrict__ deg)
{
    int e = blockIdx.x * 256 + threadIdx.x;
    if (e < EE) atomicAdd(&deg[el[e * 3]], 1.f);
}

__global__ __launch_bounds__(256) void cvt_kernel(
    const float* __restrict__ s, ushort_t* __restrict__ d, int n)
{
    int t = blockIdx.x * 256 + threadIdx.x;
    if (t < n) d[t] = bf16u(s[t]);
}

// Pack W (Kreal x N row-major fp32) into MFMA B-fragment order, bf16.
__global__ __launch_bounds__(64) void pack_kernel(
    const float* __restrict__ W, ushort_t* __restrict__ out,
    int Kreal, int N)
{
    int kt = blockIdx.x, nt = blockIdx.y, NTOT = gridDim.y;
    int lane = threadIdx.x;
    int n = nt * 16 + (lane & 15);
    int kbase = kt * 32 + (lane >> 4) * 8;
    ushort_t* o = out + ((size_t)(kt * NTOT + nt) * 64 + lane) * 8;
    #pragma unroll
    for (int j = 0; j < 8; ++j) {
        int k = kbase + j;
        o[j] = (k < Kreal) ? bf16u(W[(size_t)k * N + n]) : (ushort_t)0;
    }
}

// ---------------- MFMA stage helper ----------------
// A in LDS (32 rows, stride 584 bf16 = 73*16B, odd multiple of 16B).
// Wave w covers output cols [w*64, w*64+64) as 4 x 16-col tiles.

template<int KT, int NTOT>
__device__ __forceinline__ void mfma_stage32(
    const ushort_t (&A)[32][584], int colOff,
    const ushort_t* __restrict__ Wp, int w, int lane,
    f32x4 (&acc)[2][4])
{
    const f32x4 Z = {0.f, 0.f, 0.f, 0.f};
    #pragma unroll
    for (int mt = 0; mt < 2; ++mt)
        #pragma unroll
        for (int j = 0; j < 4; ++j) acc[mt][j] = Z;
    const int ar = lane & 15, aq = (lane >> 4) * 8;
    for (int kt = 0; kt < KT; ++kt) {
        bf16x8 a0 = *(const bf16x8*)&A[ar][colOff + kt * 32 + aq];
        bf16x8 a1 = *(const bf16x8*)&A[16 + ar][colOff + kt * 32 + aq];
        #pragma unroll
        for (int j = 0; j < 4; ++j) {
            bf16x8 b = *(const bf16x8*)(Wp + ((size_t)(kt * NTOT + w * 4 + j) * 64 + lane) * 8);
            acc[0][j] = __builtin_amdgcn_mfma_f32_16x16x32_bf16(a0, b, acc[0][j], 0, 0, 0);
            acc[1][j] = __builtin_amdgcn_mfma_f32_16x16x32_bf16(a1, b, acc[1][j], 0, 0, 0);
        }
    }
}

// ---------------- fused edge kernel (32 edges/block, 8 barriers, 4 blk/CU) ----

__global__ __launch_bounds__(256, 4) void edge_kernel(
    const int* __restrict__ el, const float* __restrict__ cw,
    const float* __restrict__ ew, const float* __restrict__ x,
    const ushort_t* __restrict__ hb16, const ushort_t* __restrict__ cab16,
    const float* __restrict__ W_rad, const float* __restrict__ b_rad,
    const ushort_t* __restrict__ pe1, const float* __restrict__ b_e1,
    const ushort_t* __restrict__ pe2, const float* __restrict__ b_e2,
    const ushort_t* __restrict__ pc1, const float* __restrict__ b_c1,
    const ushort_t* __restrict__ pc2,
    float* __restrict__ agg, float* __restrict__ xacc)
{
    // Region map per row: X = cols 0..255, Y = cols 288..543.
    // e1 reads 0..575 -> t1 in Y -> e2 reads Y, m in X -> c1 reads X,
    // t2 in Y -> c2 reads Y. m (X) survives to kernel end for agg atomics.
    __shared__ ushort_t abuf[32][584];   // 37376 B
    __shared__ float radbuf[32][16];     // radial, later phi (2048 B)
    __shared__ int rowS[32], colS[32], relS[32];
    __shared__ float ewS[32];

    const int tid = threadIdx.x, lane = tid & 63, w = tid >> 6;
    const int ar = lane & 15, aq = (lane >> 4) * 8, quad = lane >> 4;
    const int e0 = blockIdx.x * 32;

    if (tid < 32) {
        rowS[tid] = el[(e0 + tid) * 3 + 0];
        colS[tid] = el[(e0 + tid) * 3 + 1];
        relS[tid] = el[(e0 + tid) * 3 + 2];
        ewS[tid]  = ew[e0 + tid];
    }
    __syncthreads();   // B1

    // ---- staging phase: h, ca, pad, radial ----
    // h[row]/h[col]: 2048 x 16B chunks
    #pragma unroll
    for (int it = 0; it < 8; ++it) {
        int c = it * 256 + tid;
        int e = c >> 6, half = (c >> 5) & 1, idx = c & 31;
        int node = half ? colS[e] : rowS[e];
        *(uint4*)&abuf[e][half * 256 + idx * 8] =
            ((const uint4*)(hb16 + (size_t)node * 256))[idx];
    }
    // ca: 128 chunks; zero-pad 560..575: 64 chunks
    if (tid < 128) {
        int e = tid >> 2, half2 = (tid >> 1) & 1, idx = tid & 1;
        int node = half2 ? colS[e] : rowS[e];
        *(uint4*)&abuf[e][528 + half2 * 16 + idx * 8] =
            ((const uint4*)(cab16 + node * 16))[idx];
    } else if (tid < 192) {
        int c = tid - 128, e = c >> 1, idx = c & 1;
        uint4 z = {0u, 0u, 0u, 0u};
        *(uint4*)&abuf[e][560 + idx * 8] = z;
    }
    // radial: 512 items (e, ab)
    #pragma unroll
    for (int it = 0; it < 2; ++it) {
        int t = it * 256 + tid;
        int e = t >> 4, ab = t & 15, a = ab >> 2, b = ab & 3;
        int row = rowS[e], col = colS[e];
        float d0 = x[row * 12 + a * 3 + 0] - x[col * 12 + b * 3 + 0];
        float d1 = x[row * 12 + a * 3 + 1] - x[col * 12 + b * 3 + 1];
        float d2 = x[row * 12 + a * 3 + 2] - x[col * 12 + b * 3 + 2];
        radbuf[e][ab] = (d0 * d0 + d1 * d1 + d2 * d2)
                      * cw[row * CCH + a] * cw[col * CCH + b];
    }
    __syncthreads();   // B2

    // rad_feat -> abuf cols 512..527
    #pragma unroll
    for (int it = 0; it < 2; ++it) {
        int t = it * 256 + tid;
        int e = t >> 4, f = t & 15;
        float acc = b_rad[f];
        #pragma unroll
        for (int ab = 0; ab < 16; ++ab) acc += radbuf[e][ab] * W_rad[ab * 16 + f];
        abuf[e][512 + f] = bf16u(silu_f(acc));
    }
    __syncthreads();   // B3

    f32x4 acc[2][4];

    // ---- e1: reads cols 0..575 ----
    mfma_stage32<18, 16>(abuf, 0, pe1, w, lane, acc);
    __syncthreads();   // B4 (epilogue writes Y which overlaps e1 input)
    #pragma unroll
    for (int j = 0; j < 4; ++j) {
        int n = w * 64 + j * 16 + ar;
        float bj = b_e1[n];
        #pragma unroll
        for (int mt = 0; mt < 2; ++mt)
            #pragma unroll
            for (int r = 0; r < 4; ++r)
                abuf[mt * 16 + quad * 4 + r][288 + n] = bf16u(silu_f(acc[mt][j][r] + bj));
    }
    __syncthreads();   // B5

    // ---- e2: reads Y, writes m -> X (disjoint, no barrier before epilogue) ----
    mfma_stage32<8, 16>(abuf, 288, pe2, w, lane, acc);
    #pragma unroll
    for (int j = 0; j < 4; ++j) {
        int n = w * 64 + j * 16 + ar;
        float bj = b_e2[n];
        #pragma unroll
        for (int mt = 0; mt < 2; ++mt)
            #pragma unroll
            for (int r = 0; r < 4; ++r) {
                int e = mt * 16 + quad * 4 + r;
                abuf[e][n] = bf16u(silu_f(acc[mt][j][r] + bj) * ewS[e]);
            }
    }
    __syncthreads();   // B6

    // ---- c1: reads X, writes t2 -> Y ----
    mfma_stage32<8, 16>(abuf, 0, pc1, w, lane, acc);
    #pragma unroll
    for (int j = 0; j < 4; ++j) {
        int n = w * 64 + j * 16 + ar;
        float bj = b_c1[n];
        #pragma unroll
        for (int mt = 0; mt < 2; ++mt)
            #pragma unroll
            for (int r = 0; r < 4; ++r)
                abuf[mt * 16 + quad * 4 + r][288 + n] = bf16u(silu_f(acc[mt][j][r] + bj));
    }
    __syncthreads();   // B7

    // ---- c2: waves 0,1 compute phi for 16 edges each (full K), -> radbuf ----
    if (w < 2) {
        const f32x4 Z = {0.f, 0.f, 0.f, 0.f};
        f32x4 p = Z;
        #pragma unroll
        for (int kt = 0; kt < 8; ++kt) {
            bf16x8 a = *(const bf16x8*)&abuf[w * 16 + ar][288 + kt * 32 + aq];
            bf16x8 b = *(const bf16x8*)(pc2 + ((size_t)kt * 64 + lane) * 8);
            p = __builtin_amdgcn_mfma_f32_16x16x32_bf16(a, b, p, 0, 0, 0);
        }
        #pragma unroll
        for (int r = 0; r < 4; ++r)
            radbuf[w * 16 + quad * 4 + r][ar] = p[r];
    }
    __syncthreads();   // B8

    // ---- trans -> xacc (xd recomputed from L1-hot x) ----
    for (int t = tid; t < 384; t += 256) {
        int e = t / 12, r = t - e * 12, a = r / 3, k = r - a * 3;
        int row = rowS[e], col = colS[e];
        float xr = x[row * 12 + a * 3 + k];
        float s = 0.f;
        #pragma unroll
        for (int b = 0; b < 4; ++b)
            s += (xr - x[col * 12 + b * 3 + k]) * radbuf[e][a * 4 + b];
        atomicAdd(&xacc[row * 12 + a * 3 + k], 0.25f * s);
    }

    // ---- deferred agg atomics: re-read m from X, no barrier drains these ----
    #pragma unroll
    for (int j = 0; j < 4; ++j) {
        int n = w * 64 + j * 16 + ar;
        #pragma unroll
        for (int mt = 0; mt < 2; ++mt)
            #pragma unroll
            for (int r = 0; r < 4; ++r) {
                int e = mt * 16 + quad * 4 + r;
                float m = ubf2f(abuf[e][n]);
                atomicAdd(&agg[((size_t)colS[e] * RR + relS[e]) * HH + n], m);
            }
    }
}

// ---------------- fused node kernel (n1 + n2 + LN, 16 nodes/block) ----------------

__global__ __launch_bounds__(256, 3) void node_kernel(
    const float* __restrict__ agg, const float* __restrict__ hsrc,
    const ushort_t* __restrict__ pn1, const float* __restrict__ b_n1,
    const ushort_t* __restrict__ pn2, const float* __restrict__ b_n2,
    const float* __restrict__ ln_g, const float* __restrict__ ln_b,
    float* __restrict__ h_out, ushort_t* __restrict__ hb16o)
{
    // arena: nbuf (ushort [16][1032] = 33024 B) unioned with h2buf (float [16][264] = 16896 B)
    __shared__ __align__(16) char arena[33024];
    __shared__ ushort_t tbuf[16][264];
    __shared__ float redS[16][16], red2S[16][16], muS[16], rsS[16];
    ushort_t (*nbuf)[1032] = (ushort_t(*)[1032])arena;
    float (*h2buf)[264] = (float(*)[264])arena;

    const int tid = threadIdx.x, lane = tid & 63, w = tid >> 6;
    const int n0 = blockIdx.x * 16;
    const int ar = lane & 15, aq = (lane >> 4) * 8;
    const f32x4 Z = {0.f, 0.f, 0.f, 0.f};

    f32x4 acc[4] = {Z, Z, Z, Z};
    for (int chunk = 0; chunk < 2; ++chunk) {
        for (int t = tid; t < 4096; t += 256) {
            int node = t >> 8, i4 = t & 255;
            int g4 = chunk * 256 + i4;        // float4 index over K=2048
            float4 v;
            if (g4 < 448) v = ((const float4*)(agg + (size_t)(n0 + node) * 1792))[g4];
            else          v = ((const float4*)(hsrc + (size_t)(n0 + node) * 256))[g4 - 448];
            ushort4 u;
            u.x = bf16u(v.x); u.y = bf16u(v.y); u.z = bf16u(v.z); u.w = bf16u(v.w);
            *(ushort4*)&nbuf[node][i4 * 4] = u;
        }
        __syncthreads();
        for (int kt = 0; kt < 32; ++kt) {
            bf16x8 a = *(const bf16x8*)&nbuf[ar][kt * 32 + aq];
            int ktg = chunk * 32 + kt;
            #pragma unroll
            for (int j = 0; j < 4; ++j) {
                bf16x8 b = *(const bf16x8*)(pn1 + ((size_t)(ktg * 16 + w * 4 + j) * 64 + lane) * 8);
                acc[j] = __builtin_amdgcn_mfma_f32_16x16x32_bf16(a, b, acc[j], 0, 0, 0);
            }
        }
        __syncthreads();
    }
    #pragma unroll
    for (int j = 0; j < 4; ++j) {
        int n = w * 64 + j * 16 + ar;
        float bj = b_n1[n];
        #pragma unroll
        for (int r = 0; r < 4; ++r)
            tbuf[(lane >> 4) * 4 + r][n] = bf16u(silu_f(acc[j][r] + bj));
    }
    __syncthreads();
    f32x4 acc2[4] = {Z, Z, Z, Z};
    for (int kt = 0; kt < 8; ++kt) {
        bf16x8 a = *(const bf16x8*)&tbuf[ar][kt * 32 + aq];
        #pragma unroll
        for (int j = 0; j < 4; ++j) {
            bf16x8 b = *(const bf16x8*)(pn2 + ((size_t)(kt * 16 + w * 4 + j) * 64 + lane) * 8);
            acc2[j] = __builtin_amdgcn_mfma_f32_16x16x32_bf16(a, b, acc2[j], 0, 0, 0);
        }
    }
    float hv[4][4];
    #pragma unroll
    for (int j = 0; j < 4; ++j) {
        int n = w * 64 + j * 16 + ar;
        float bj = b_n2[n];
        #pragma unroll
        for (int r = 0; r < 4; ++r) {
            hv[j][r] = acc2[j][r] + bj;
            h2buf[(lane >> 4) * 4 + r][n] = hv[j][r];
        }
    }
    __syncthreads();
    {
        int node = tid >> 4, c = tid & 15;
        float s = 0.f, s2 = 0.f;
        #pragma unroll
        for (int i = 0; i < 16; ++i) {
            float v = h2buf[node][c * 16 + i];
            s += v; s2 += v * v;
        }
        redS[node][c] = s; red2S[node][c] = s2;
    }
    __syncthreads();
    if (tid < 16) {
        float s = 0.f, s2 = 0.f;
        #pragma unroll
        for (int c = 0; c < 16; ++c) { s += redS[tid][c]; s2 += red2S[tid][c]; }
        float mu = s * (1.f / 256.f);
        muS[tid] = mu;
        rsS[tid] = rsqrtf(s2 * (1.f / 256.f) - mu * mu + EPSV);
    }
    __syncthreads();
    #pragma unroll
    for (int j = 0; j < 4; ++j) {
        int n = w * 64 + j * 16 + ar;
        float g = ln_g[n], bb = ln_b[n];
        #pragma unroll
        for (int r = 0; r < 4; ++r) {
            int row = (lane >> 4) * 4 + r;
            float v = (hv[j][r] - muS[row]) * rsS[row] * g + bb;
            h_out[(size_t)(n0 + row) * HH + n] = v;
            hb16o[(size_t)(n0 + row) * HH + n] = bf16u(v);
        }
    }
}

__global__ __launch_bounds__(256) void xout_kernel(
    const float* __restrict__ x_in, const float* __restrict__ xacc,
    const float* __restrict__ deg, float* __restrict__ x_out)
{
    int t = blockIdx.x * 256 + threadIdx.x;
    if (t < NN * 12) {
        int n = t / 12;
        float c = fmaxf(deg[n], 1.f);
        x_out[t] = x_in[t] + xacc[t] / c;
    }
}

// ---------------- launcher ----------------

extern "C" void kernel_launch(void* const* d_in, const int* in_sizes, int n_in,
                              void* d_out, int out_size, void* d_ws, size_t ws_size,
                              hipStream_t stream)
{
    const float* input  = (const float*)d_in[0];
    const float* coords = (const float*)d_in[1];
    const float* cattr  = (const float*)d_in[2];
    const float* cwts   = (const float*)d_in[3];
    const float* ewts   = (const float*)d_in[4];
    const int*   elist  = (const int*)d_in[5];
    const float* W_rad  = (const float*)d_in[6];
    const float* b_rad  = (const float*)d_in[7];
    const float* W_e1   = (const float*)d_in[8];
    const float* b_e1   = (const float*)d_in[9];
    const float* W_e2   = (const float*)d_in[10];
    const float* b_e2   = (const float*)d_in[11];
    const float* W_c1   = (const float*)d_in[12];
    const float* b_c1   = (const float*)d_in[13];
    const float* W_c2   = (const float*)d_in[14];
    const float* W_n1   = (const float*)d_in[15];
    const float* b_n1   = (const float*)d_in[16];
    const float* W_n2   = (const float*)d_in[17];
    const float* b_n2   = (const float*)d_in[18];
    const float* ln_g   = (const float*)d_in[19];
    const float* ln_b   = (const float*)d_in[20];

    float* wsf  = (float*)d_ws;
    float* ca   = wsf;
    float* deg  = ca + 160000;
    float* agg  = deg + 10000;
    float* xacc = agg + (size_t)NN * RR * HH;
    float* hbuf = xacc + 120000;
    float* xbuf = hbuf + (size_t)NN * HH;
    ushort_t* ub = (ushort_t*)(xbuf + 120000);
    ushort_t* hb16  = ub;
    ushort_t* cab16 = hb16 + 2560000;
    ushort_t* pe1   = cab16 + 160000;
    ushort_t* pe2   = pe1 + 294912;
    ushort_t* pc1   = pe2 + 131072;
    ushort_t* pc2   = pc1 + 131072;
    ushort_t* pn1   = pc2 + 8192;
    ushort_t* pn2   = pn1 + 1048576;

    hipMemsetAsync(deg, 0, (size_t)NN * sizeof(float), stream);
    ca_kernel<<<(NN * CF + 255) / 256, 256, 0, stream>>>(cattr, cwts, ca);
    deg_kernel<<<(EE + 255) / 256, 256, 0, stream>>>(elist, deg);
    cvt_kernel<<<(NN * HH + 255) / 256, 256, 0, stream>>>(input, hb16, NN * HH);
    cvt_kernel<<<(NN * CF + 255) / 256, 256, 0, stream>>>(ca, cab16, NN * CF);

    for (int l = 0; l < 2; ++l) {
        pack_kernel<<<dim3(18, 16), 64, 0, stream>>>(W_e1 + (size_t)l * 560 * 256, pe1 + (size_t)l * 147456, 560, 256);
        pack_kernel<<<dim3(8, 16), 64, 0, stream>>>(W_e2 + (size_t)l * 65536, pe2 + (size_t)l * 65536, 256, 256);
        pack_kernel<<<dim3(8, 16), 64, 0, stream>>>(W_c1 + (size_t)l * 65536, pc1 + (size_t)l * 65536, 256, 256);
        pack_kernel<<<dim3(8, 1),  64, 0, stream>>>(W_c2 + (size_t)l * 4096,  pc2 + (size_t)l * 4096,  256, 16);
        pack_kernel<<<dim3(64, 16), 64, 0, stream>>>(W_n1 + (size_t)l * 524288, pn1 + (size_t)l * 524288, 2048, 256);
        pack_kernel<<<dim3(8, 16), 64, 0, stream>>>(W_n2 + (size_t)l * 65536, pn2 + (size_t)l * 65536, 256, 256);
    }

    for (int l = 0; l < 2; ++l) {
        const float* x_in = (l == 0) ? coords : xbuf;
        const float* h_in_f = (l == 0) ? input : hbuf;
        float* h_out = (l == 0) ? hbuf : (float*)d_out;
        float* x_out = (l == 0) ? xbuf : ((float*)d_out + (size_t)NN * HH);

        hipMemsetAsync(agg, 0, (size_t)NN * RR * HH * sizeof(float), stream);
        hipMemsetAsync(xacc, 0, (size_t)NN * 12 * sizeof(float), stream);

        edge_kernel<<<EE / 32, 256, 0, stream>>>(
            elist, cwts, ewts, x_in, hb16, cab16,
            W_rad + l * 256, b_rad + l * 16,
            pe1 + (size_t)l * 147456, b_e1 + l * HH,
            pe2 + (size_t)l * 65536,  b_e2 + l * HH,
            pc1 + (size_t)l * 65536,  b_c1 + l * HH,
            pc2 + (size_t)l * 4096,
            agg, xacc);

        node_kernel<<<NN / 16, 256, 0, stream>>>(
            agg, h_in_f,
            pn1 + (size_t)l * 524288, b_n1 + l * HH,
            pn2 + (size_t)l * 65536,  b_n2 + l * HH,
            ln_g + l * HH, ln_b + l * HH,
            h_out, hb16);

        xout_kernel<<<(NN * 12 + 255) / 256, 256, 0, stream>>>(
            x_in, xacc, deg, x_out);
    }
}